// Round 2
// baseline (955.620 us; speedup 1.0000x reference)
//
#include <hip/hip_runtime.h>
#include <cmath>

typedef unsigned long long u64;

// Problem constants
#define HD    256
#define NCLS  80
#define NBQ   32000      // B*Q = 16*2000
#define QN    2000
#define NSORT 2048
#define PNMS  1000
#define NB    16

// Output float offsets (concatenated return tuple)
#define O_PB   0         // pred_boxes  [16,2000,4]
#define O_PL   128000    // pred_logits [16,2000,80]
#define O_PRB  2688000   // prop_boxes  [16,1000,4]
#define O_PRS  2752000   // prop_scores [16,1000]
#define O_PRM  2768000   // prop_mask   [16,1000]

// ---------------------------------------------------------------------------
// Fused 3-layer MLP, all-f64 intermediates (decision-grade precision).
// 16 rows per block, 256 threads (thread = output column for layers 1/2).
__global__ __launch_bounds__(256)
void mlp_fused(const float* __restrict__ hs, const float* __restrict__ w1,
               const float* __restrict__ b1, const float* __restrict__ w2,
               const float* __restrict__ b2, const float* __restrict__ w3,
               const float* __restrict__ b3, double* __restrict__ delta) {
  __shared__ float  hsS[16][260];   // f32 input tile (pad 260: 16B-aligned rows)
  __shared__ double hbuf[16][258];  // f64 hidden activations
  const int tid = threadIdx.x;
  const int row0 = blockIdx.x * 16;

  // stage hs tile (coalesced float4)
  #pragma unroll
  for (int v = 0; v < 4; v++) {
    int idx = v * 256 + tid;                 // 0..1023 float4s
    int r = idx >> 6, c = (idx & 63) << 2;
    float4 a = *(const float4*)(hs + (size_t)(row0 + r) * HD + c);
    *(float4*)&hsS[r][c] = a;
  }
  __syncthreads();

  // layer 1: h1 = relu(hs @ w1 + b1), f64 accum
  double acc[16];
  #pragma unroll
  for (int r = 0; r < 16; r++) acc[r] = 0.0;
  for (int k = 0; k < HD; k += 2) {
    double wa = (double)w1[(size_t)k * HD + tid];
    double wb = (double)w1[(size_t)(k + 1) * HD + tid];
    #pragma unroll
    for (int r = 0; r < 16; r++) {
      float2 a2 = *(const float2*)&hsS[r][k];
      acc[r] = fma((double)a2.x, wa, acc[r]);
      acc[r] = fma((double)a2.y, wb, acc[r]);
    }
  }
  {
    double bias = (double)b1[tid];
    #pragma unroll
    for (int r = 0; r < 16; r++) {
      double v = acc[r] + bias;
      hbuf[r][tid] = v > 0.0 ? v : 0.0;
    }
  }
  __syncthreads();

  // layer 2: h2 = relu(h1 @ w2 + b2)
  #pragma unroll
  for (int r = 0; r < 16; r++) acc[r] = 0.0;
  for (int k = 0; k < HD; k += 2) {
    double wa = (double)w2[(size_t)k * HD + tid];
    double wb = (double)w2[(size_t)(k + 1) * HD + tid];
    #pragma unroll
    for (int r = 0; r < 16; r++) {
      double2 a2 = *(const double2*)&hbuf[r][k];
      acc[r] = fma(a2.x, wa, acc[r]);
      acc[r] = fma(a2.y, wb, acc[r]);
    }
  }
  __syncthreads();   // all reads of h1 done before overwrite
  {
    double bias = (double)b2[tid];
    #pragma unroll
    for (int r = 0; r < 16; r++) {
      double v = acc[r] + bias;
      hbuf[r][tid] = v > 0.0 ? v : 0.0;
    }
  }
  __syncthreads();

  // layer 3: delta = h2 @ w3 + b3  (64 outputs, 4-way k-split + shfl reduce)
  const int outi = tid >> 2;          // 0..63
  const int kp = tid & 3;
  const int r = outi >> 2, c = outi & 3;
  double d = 0.0;
  for (int k = kp * 64; k < kp * 64 + 64; k++)
    d = fma(hbuf[r][k], (double)w3[k * 4 + c], d);
  d += __shfl_xor(d, 1);
  d += __shfl_xor(d, 2);
  if (kp == 0)
    delta[(size_t)(row0 + r) * 4 + c] = d + (double)b3[c];
}

// ---------------------------------------------------------------------------
// logits = hs_last @ cls_w[256,80] + cls_b (f64 accum); f64 row-max -> obj.
__global__ __launch_bounds__(256)
void cls_gemm(const float* __restrict__ Ain, const float* __restrict__ CW,
              const float* __restrict__ CB, float* __restrict__ logits,
              double* __restrict__ obj) {
  __shared__ __align__(16) float Ws[128 * NCLS];  // 40KB, staged in 2 phases
  const int tid = threadIdx.x;
  const int r = tid >> 2, cq = tid & 3;
  const int row = blockIdx.x * 64 + r;
  const float* a = Ain + (size_t)row * HD;
  double acc[20] = {};
  for (int ph = 0; ph < 2; ph++) {
    __syncthreads();
    #pragma unroll
    for (int v = 0; v < 10; v++) {
      int idx = v * 256 + tid;
      ((float4*)Ws)[idx] = ((const float4*)CW)[ph * 2560 + idx];
    }
    __syncthreads();
    for (int k4 = 0; k4 < 128; k4 += 4) {
      float4 av = *(const float4*)(a + ph * 128 + k4);
      float af[4] = {av.x, av.y, av.z, av.w};
      #pragma unroll
      for (int i = 0; i < 4; i++) {
        double ad = (double)af[i];
        const float* wr = &Ws[(k4 + i) * NCLS + cq * 20];
        #pragma unroll
        for (int j = 0; j < 20; j += 4) {
          float4 wv = *(const float4*)(wr + j);
          acc[j + 0] = fma(ad, (double)wv.x, acc[j + 0]);
          acc[j + 1] = fma(ad, (double)wv.y, acc[j + 1]);
          acc[j + 2] = fma(ad, (double)wv.z, acc[j + 2]);
          acc[j + 3] = fma(ad, (double)wv.w, acc[j + 3]);
        }
      }
    }
  }
  double mx = -INFINITY;
  float vals[20];
  #pragma unroll
  for (int j = 0; j < 20; j++) {
    double cvl = acc[j] + (double)CB[cq * 20 + j];
    vals[j] = (float)cvl;
    mx = fmax(mx, cvl);
  }
  float* lrow = logits + (size_t)row * NCLS + cq * 20;
  #pragma unroll
  for (int j = 0; j < 20; j += 4)
    *(float4*)(lrow + j) = make_float4(vals[j], vals[j+1], vals[j+2], vals[j+3]);
  mx = fmax(mx, __shfl_xor(mx, 1));
  mx = fmax(mx, __shfl_xor(mx, 2));
  if (cq == 0) obj[row] = mx;
}

// ---------------------------------------------------------------------------
// f64 box decode + score masking.
__global__ __launch_bounds__(256)
void decode64(const double* __restrict__ D, const float* __restrict__ ref_last,
              const double* __restrict__ obj, float* __restrict__ pb_out,
              double4* __restrict__ boxes, double* __restrict__ scores,
              const int* __restrict__ ihp, const int* __restrict__ iwp) {
  int idx = blockIdx.x * 256 + threadIdx.x;  // 0..31999
  double dx = D[idx * 4 + 0], dy = D[idx * 4 + 1];
  double dz = D[idx * 4 + 2], dw = D[idx * 4 + 3];
  float4 rf = ((const float4*)ref_last)[idx];
  double rx = rf.x, ry = rf.y, rz = rf.z, rw = rf.w;
  double sw = (double)(*iwp), sh = (double)(*ihp);
  double cx = dx * rz + rx;
  double cy = dy * rw + ry;
  double w  = exp(dz) * rz;
  double h  = exp(dw) * rw;
  ((float4*)pb_out)[idx] = make_float4((float)cx, (float)cy, (float)w, (float)h);
  double x1 = (cx - 0.5 * w) * sw;
  double y1 = (cy - 0.5 * h) * sh;
  double x2 = (cx + 0.5 * w) * sw;
  double y2 = (cy + 0.5 * h) * sh;
  double4 bx; bx.x = x1; bx.y = y1; bx.z = x2; bx.w = y2;
  boxes[idx] = bx;
  bool valid = ((x2 - x1) > 0.0) && ((y2 - y1) > 0.0);
  scores[idx] = valid ? obj[idx] : -INFINITY;
}

// ---------------------------------------------------------------------------
// Per-batch stable descending sort on (f64-score sortable key, 2047-q).
__global__ __launch_bounds__(256)
void sort64(const double* __restrict__ scores, const double4* __restrict__ boxes,
            double4* __restrict__ sbox, double* __restrict__ sscore) {
  __shared__ u64 kh[NSORT];
  __shared__ unsigned kl[NSORT];
  const int b = blockIdx.x, tid = threadIdx.x;
  const double* sc = scores + (size_t)b * QN;
  for (int q = tid; q < NSORT; q += 256) {
    u64 h = 0ull; unsigned l = 0u;
    if (q < QN) {
      u64 u = (u64)__double_as_longlong(sc[q]);
      u = (u >> 63) ? ~u : (u | 0x8000000000000000ull);
      h = u; l = (unsigned)(2047 - q);
    }
    kh[q] = h; kl[q] = l;
  }
  __syncthreads();
  for (int k = 2; k <= NSORT; k <<= 1) {
    for (int j = k >> 1; j > 0; j >>= 1) {
      for (int i = tid; i < NSORT; i += 256) {
        int ixj = i ^ j;
        if (ixj > i) {
          u64 ha = kh[i], hc = kh[ixj];
          unsigned la = kl[i], lc = kl[ixj];
          bool altc = (ha < hc) || (ha == hc && la < lc);
          bool agtc = (ha > hc) || (ha == hc && la > lc);
          bool up = (i & k) == 0;          // descending overall
          if (up ? altc : agtc) {
            kh[i] = hc; kh[ixj] = ha;
            kl[i] = lc; kl[ixj] = la;
          }
        }
      }
      __syncthreads();
    }
  }
  for (int s = tid; s < NSORT; s += 256) {
    u64 h = kh[s];
    double4 bx; bx.x = 0.0; bx.y = 0.0; bx.z = 0.0; bx.w = 0.0;
    double ss = -INFINITY;
    if (h) {
      int q = 2047 - (int)kl[s];
      bx = boxes[(size_t)b * QN + q];
      ss = sc[q];
    }
    sbox[(size_t)b * NSORT + s] = bx;
    sscore[(size_t)b * NSORT + s] = ss;
  }
}

// ---------------------------------------------------------------------------
// f64 IoU suppression bitmask: bit j of row i set iff iou(i,j)>0.7 && j>i && j<2000.
__global__ __launch_bounds__(256)
void iou64(const double4* __restrict__ sbox, u64* __restrict__ sup) {
  __shared__ double4 Bj[1024];
  __shared__ double  Aj[1024];
  const int b = blockIdx.y, tid = threadIdx.x;
  const int i0 = blockIdx.x * 16;
  const int wid = tid >> 6, lane = tid & 63;
  const double4* sb = sbox + (size_t)b * NSORT;
  for (int chunk = 0; chunk < 2; chunk++) {
    const int jbase = chunk * 1024;
    for (int v = tid; v < 1024; v += 256) {
      double4 bj = sb[jbase + v];
      Bj[v] = bj;
      Aj[v] = (bj.z - bj.x) * (bj.w - bj.y);
    }
    __syncthreads();
    for (int ii = 0; ii < 16; ii++) {
      const int i = i0 + ii;
      double4 bi = sb[i];
      double ai = (bi.z - bi.x) * (bi.w - bi.y);
      #pragma unroll
      for (int t = 0; t < 4; t++) {
        int jl = t * 256 + tid;
        int j = jbase + jl;
        double4 bj = Bj[jl];
        double ltx = fmax(bi.x, bj.x), lty = fmax(bi.y, bj.y);
        double rbx = fmin(bi.z, bj.z), rby = fmin(bi.w, bj.w);
        double iw  = fmax(rbx - ltx, 0.0);
        double ihh = fmax(rby - lty, 0.0);
        double inter = iw * ihh;
        double uni = ai + Aj[jl] - inter;
        double iou = (uni > 0.0) ? (inter / uni) : 0.0;
        bool pred = (iou > 0.7) && (j > i) && (j < QN);
        u64 m = __ballot(pred);
        if (lane == 0)
          sup[((size_t)b * NSORT + i) * 32 + (jbase >> 6) + t * 4 + wid] = m;
      }
    }
    __syncthreads();
  }
}

// ---------------------------------------------------------------------------
// Serial NMS scan (1 wave/batch) + compaction to the output slots.
__global__ __launch_bounds__(64)
void nms_scan(const u64* __restrict__ sup, const double4* __restrict__ sbox,
              const double* __restrict__ sscore, float* __restrict__ out) {
  const int b = blockIdx.x, lane = threadIdx.x;
  float* prb = out + O_PRB + b * (PNMS * 4);
  float* prs = out + O_PRS + b * PNMS;
  float* prm = out + O_PRM + b * PNMS;
  for (int s = lane; s < PNMS; s += 64) {
    ((float4*)prb)[s] = make_float4(0.f, 0.f, 0.f, 0.f);
    prs[s] = -INFINITY;
    prm[s] = 0.f;
  }
  __syncthreads();
  const double* ssc = sscore + (size_t)b * NSORT;
  u64 removed = 0ull;
  for (int w = 0; w < 32; w++) {
    u64 bal = __ballot(ssc[w * 64 + lane] != -INFINITY);
    if (lane == w) removed = ~bal;     // invalid/pad entries start removed
  }
  const u64* supb = sup + (size_t)b * NSORT * 32;
  u64 buf[16];
  #pragma unroll
  for (int t = 0; t < 16; t++) buf[t] = (lane < 32) ? supb[(size_t)t * 32 + lane] : 0ull;
  for (int base = 0; base < QN; base += 16) {
    u64 cur[16];
    #pragma unroll
    for (int t = 0; t < 16; t++) cur[t] = buf[t];
    int nb = base + 16;
    #pragma unroll
    for (int t = 0; t < 16; t++)
      buf[t] = (lane < 32 && (nb + t) < QN) ? supb[(size_t)(nb + t) * 32 + lane] : 0ull;
    #pragma unroll
    for (int t = 0; t < 16; t++) {
      int i = base + t;
      u64 w = __shfl(removed, i >> 6);
      if (!((w >> (i & 63)) & 1ull)) removed |= cur[t];
    }
  }
  u64 keep = (lane < 32) ? ~removed : 0ull;
  int pc = __popcll(keep);
  int incl = pc;
  for (int off = 1; off < 64; off <<= 1) {
    int n = __shfl_up(incl, off);
    if (lane >= off) incl += n;
  }
  int rank = incl - pc;
  u64 kw = keep;
  while (kw) {
    int bit = __ffsll((long long)kw) - 1;
    kw &= kw - 1;
    if (rank < PNMS) {
      int j = lane * 64 + bit;
      double4 bv = sbox[(size_t)b * NSORT + j];
      ((float4*)prb)[rank] = make_float4((float)bv.x, (float)bv.y,
                                         (float)bv.z, (float)bv.w);
      prs[rank] = (float)ssc[j];
      prm[rank] = 1.f;
    }
    rank++;
  }
}

// ---------------------------------------------------------------------------
extern "C" void kernel_launch(void* const* d_in, const int* in_sizes, int n_in,
                              void* d_out, int out_size, void* d_ws, size_t ws_size,
                              hipStream_t stream) {
  const float* hs  = (const float*)d_in[0];
  const float* ref = (const float*)d_in[1];
  const float* w1  = (const float*)d_in[2];
  const float* b1  = (const float*)d_in[3];
  const float* w2  = (const float*)d_in[4];
  const float* b2  = (const float*)d_in[5];
  const float* w3  = (const float*)d_in[6];
  const float* b3  = (const float*)d_in[7];
  const float* cw  = (const float*)d_in[8];
  const float* cb  = (const float*)d_in[9];
  const int*   ihp = (const int*)d_in[10];
  const int*   iwp = (const int*)d_in[11];
  float* out = (float*)d_out;

  const float* hs_last  = hs  + (size_t)5 * NBQ * HD;
  const float* ref_last = ref + (size_t)5 * NBQ * 4;

  // workspace layout (all f64, ~12.3 MB)
  double4* boxes  = (double4*)d_ws;                 // 32000  (1,024,000 B)
  double4* sbox   = boxes + NBQ;                    // 32768  (1,048,576 B)
  double*  delta  = (double*)(sbox + NB * NSORT);   // 128000 (1,024,000 B)
  double*  obj    = delta + 128000;                 // 32000
  double*  scores = obj + NBQ;                      // 32000
  double*  sscore = scores + NBQ;                   // 32768
  u64*     sup    = (u64*)(sscore + NB * NSORT);    // 1,048,576 u64 (8 MB)

  mlp_fused<<<2000, 256, 0, stream>>>(hs_last, w1, b1, w2, b2, w3, b3, delta);
  cls_gemm<<<500, 256, 0, stream>>>(hs_last, cw, cb, out + O_PL, obj);
  decode64<<<125, 256, 0, stream>>>(delta, ref_last, obj, out + O_PB, boxes,
                                    scores, ihp, iwp);
  sort64<<<NB, 256, 0, stream>>>(scores, boxes, sbox, sscore);
  iou64<<<dim3(128, NB), 256, 0, stream>>>(sbox, sup);
  nms_scan<<<NB, 64, 0, stream>>>(sup, sbox, sscore, out);
}